// Round 8
// baseline (938.009 us; speedup 1.0000x reference)
//
#include <hip/hip_runtime.h>

#define N_NODES  50000
#define N_EDGES  640000
#define N_GRAPHS 500
static constexpr float BN_EPS = 1e-5f;
#define SCAN_NB ((N_NODES + 255) / 256)   // 196 blocks

// ---------------------------------------------------------------------------
__global__ void k_degcnt(const int* __restrict__ dst, const float* __restrict__ w,
                         float* __restrict__ wdeg, int* __restrict__ cnt, int E) {
    int i = blockIdx.x * blockDim.x + threadIdx.x;
    if (i < E) {
        int d = dst[i];
        atomicAdd(&wdeg[d], w[i]);
        atomicAdd(&cnt[d], 1);
    }
}

__global__ void k_dinv_gcnt(float* __restrict__ wdeg, const int* __restrict__ batch,
                            float* __restrict__ gcnt, int n) {
    int i = blockIdx.x * blockDim.x + threadIdx.x;
    if (i < n) {
        wdeg[i] = rsqrtf(wdeg[i] + 1.0f);
        atomicAdd(&gcnt[batch[i]], 1.0f);
    }
}

// --- 3-phase hierarchical exclusive scan of cnt[N] -> offs[N+1] (+cursor) ---
__global__ void k_scan1(const int* __restrict__ cnt, int* __restrict__ bsum, int n) {
    __shared__ int red[256];
    int i = blockIdx.x * 256 + threadIdx.x;
    red[threadIdx.x] = (i < n) ? cnt[i] : 0;
    __syncthreads();
    for (int off = 128; off > 0; off >>= 1) {
        if (threadIdx.x < off) red[threadIdx.x] += red[threadIdx.x + off];
        __syncthreads();
    }
    if (threadIdx.x == 0) bsum[blockIdx.x] = red[0];
}

__global__ void k_scan2(const int* __restrict__ bsum, int* __restrict__ bpre, int nb) {
    __shared__ int part[256];
    int t = threadIdx.x;
    part[t] = (t < nb) ? bsum[t] : 0;
    __syncthreads();
    for (int off = 1; off < 256; off <<= 1) {
        int v = (t >= off) ? part[t - off] : 0;
        __syncthreads();
        part[t] += v;
        __syncthreads();
    }
    if (t < nb) bpre[t] = (t == 0) ? 0 : part[t - 1];
}

__global__ void k_scan3(const int* __restrict__ cnt, const int* __restrict__ bpre,
                        int* __restrict__ offs, int* __restrict__ cursor, int n) {
    __shared__ int part[256];
    int i = blockIdx.x * 256 + threadIdx.x;
    int t = threadIdx.x;
    int v = (i < n) ? cnt[i] : 0;
    part[t] = v;
    __syncthreads();
    for (int off = 1; off < 256; off <<= 1) {
        int u = (t >= off) ? part[t - off] : 0;
        __syncthreads();
        part[t] += u;
        __syncthreads();
    }
    int excl = bpre[blockIdx.x] + part[t] - v;
    if (i < n) {
        offs[i] = excl;
        cursor[i] = excl;
    }
    if (i == n - 1) offs[n] = N_EDGES;
}

__global__ void k_fill(const int* __restrict__ src, const int* __restrict__ dst,
                       const float* __restrict__ w, const float* __restrict__ dinv,
                       int* __restrict__ cursor, int2* __restrict__ csr, int E) {
    int e = blockIdx.x * blockDim.x + threadIdx.x;
    if (e < E) {
        int s = src[e], d = dst[e];
        int pos = atomicAdd(&cursor[d], 1);
        csr[pos] = make_int2(s, __float_as_int(dinv[s] * w[e] * dinv[d]));
    }
}

// Fold bias+BN into per-channel affine. Layer1 additionally folds W1 (rank-1).
__global__ void k_bnprep_all(
    const float* W1,
    const float* b1, const float* g1, const float* be1, const float* m1, const float* v1,
    const float* b2, const float* g2, const float* be2, const float* m2, const float* v2,
    const float* b3, const float* g3, const float* be3, const float* m3, const float* v3,
    float* kA1, float* kB1, float* kA2, float* kB2, float* kA3, float* kB3) {
    int t = threadIdx.x;
    if (t < 64) {
        float s = g1[t] * rsqrtf(v1[t] + BN_EPS);
        kA1[t] = W1[t] * s;
        kB1[t] = (b1[t] - m1[t]) * s + be1[t];
    } else if (t < 192) {
        int c = t - 64;
        float s = g2[c] * rsqrtf(v2[c] + BN_EPS);
        kA2[c] = s; kB2[c] = (b2[c] - m2[c]) * s + be2[c];
    } else if (t < 320) {
        int c = t - 192;
        float s = g3[c] * rsqrtf(v3[c] + BN_EPS);
        kA3[c] = s; kB3[c] = (b3[c] - m3[c]) * s + be3[c];
    }
}

// Layer-1 scalar aggregation over the 200KB x table.
__global__ void k_aggx(const int* __restrict__ offs, const int2* __restrict__ csr,
                       const float* __restrict__ x, const float* __restrict__ dinv,
                       float* __restrict__ aggx, int n) {
    int i = blockIdx.x * blockDim.x + threadIdx.x;
    if (i >= n) return;
    float acc = 0.f;
    int e0 = offs[i], e1 = offs[i + 1];
    for (int j = e0; j < e1; ++j) {
        int2 e = csr[j];
        acc += x[e.x] * __int_as_float(e.y);
    }
    float di = dinv[i];
    aggx[i] = acc + x[i] * di * di;
}

// ---------------------------------------------------------------------------
// Fused layer-1-matmul + layer-2 aggregation.
__global__ void k_gather2F(const int* __restrict__ offs, const int2* __restrict__ csr,
                           const float* __restrict__ aggx, const float* __restrict__ dinv,
                           const float* __restrict__ kA1, const float* __restrict__ kB1,
                           float* __restrict__ agg2, int n) {
    int gid = blockIdx.x * blockDim.x + threadIdx.x;
    int node = gid >> 4;
    if (node >= n) return;
    int c4 = (gid & 15) * 4;
    float4 wa = *(const float4*)(kA1 + c4);
    float4 wb = *(const float4*)(kB1 + c4);
    float4 acc = {0.f, 0.f, 0.f, 0.f};
    int e0 = offs[node], e1 = offs[node + 1];
    for (int j = e0; j < e1; ++j) {
        int2 e = csr[j];
        float a = aggx[e.x];
        float nm = __int_as_float(e.y);
        acc.x += nm * fmaxf(a * wa.x + wb.x, 0.f);
        acc.y += nm * fmaxf(a * wa.y + wb.y, 0.f);
        acc.z += nm * fmaxf(a * wa.z + wb.z, 0.f);
        acc.w += nm * fmaxf(a * wa.w + wb.w, 0.f);
    }
    float di = dinv[node];
    float d2 = di * di;
    float a = aggx[node];
    acc.x += d2 * fmaxf(a * wa.x + wb.x, 0.f);
    acc.y += d2 * fmaxf(a * wa.y + wb.y, 0.f);
    acc.z += d2 * fmaxf(a * wa.z + wb.z, 0.f);
    acc.w += d2 * fmaxf(a * wa.w + wb.w, 0.f);
    *(float4*)(agg2 + (size_t)node * 64 + c4) = acc;
}

// ---------------------------------------------------------------------------
// Channel-sliced gather (layer 3): slice = blockIdx%8 -> XCD-local 3.2MB table.
__global__ void k_gatherS16(const int* __restrict__ offs, const int2* __restrict__ csr,
                            const float* __restrict__ Hs, const float* __restrict__ dinv,
                            float* __restrict__ aggs, int n) {
    int slice = blockIdx.x & 7;
    int node = (blockIdx.x >> 3) * 64 + threadIdx.x / 4;
    if (node >= n) return;
    int cq = (threadIdx.x % 4) * 4;
    const float* Hb = Hs + (size_t)slice * ((size_t)n * 16);
    float4 acc = {0.f, 0.f, 0.f, 0.f};
    int e0 = offs[node], e1 = offs[node + 1];
    for (int j = e0; j < e1; ++j) {
        int2 e = csr[j];
        float nm = __int_as_float(e.y);
        float4 hv = *(const float4*)(Hb + (size_t)e.x * 16 + cq);
        acc.x += hv.x * nm;
        acc.y += hv.y * nm;
        acc.z += hv.z * nm;
        acc.w += hv.w * nm;
    }
    float di = dinv[node];
    float d2 = di * di;
    float4 hv = *(const float4*)(Hb + (size_t)node * 16 + cq);
    acc.x += hv.x * d2;
    acc.y += hv.y * d2;
    acc.z += hv.z * d2;
    acc.w += hv.w * d2;
    *(float4*)(aggs + (size_t)slice * ((size_t)n * 16) + (size_t)node * 16 + cq) = acc;
}

// ---------------------------------------------------------------------------
// Register-tiled matmul: 32 nodes/block, x-tile AND W staged in LDS.
// K=64: one 32KB W tile; K=128: two 64-row half-passes (acc persists).
// Hot K-loop touches LDS only — no global loads (round-7 evidence: in-loop
// global W loads left VALUBusy at 17.8% with duration invariant to occupancy).
// Each thread: 4 nodes x 4 channels (4 float4 acc). Rolled K-loop (round-6:
// forced unroll + prefetch spilled at 256 VGPR).
template <int K, int S, bool POOL>
__global__ __launch_bounds__(256) void k_mmT(
    const float* __restrict__ Xs, const float* __restrict__ W,
    const float* __restrict__ kA, const float* __restrict__ kB,
    const float* __restrict__ res, const int* __restrict__ batch,
    float* __restrict__ outs, float* __restrict__ pooled, int n) {
    constexpr int CS = K / S;
    constexpr int KP = K + 4;            // padded LDS row stride (floats)
    constexpr int KH = 64;               // W half-pass rows
    constexpr int NPASS = K / KH;
    __shared__ float xl[32 * KP];
    __shared__ float wl[KH * 128];       // 32 KB
    int base = blockIdx.x * 32;
    int tid = threadIdx.x;
    constexpr int TOT4 = 32 * K / 4;
    constexpr int SL4 = 32 * CS / 4;
    for (int i = tid; i < TOT4; i += 256) {
        int slice = i / SL4;
        int rem = i - slice * SL4;
        int nl = rem / (CS / 4);
        int off4 = (rem % (CS / 4)) * 4;
        int node = base + nl;
        float4 v = {0.f, 0.f, 0.f, 0.f};
        if (node < n)
            v = *(const float4*)(Xs + (size_t)slice * ((size_t)n * CS) + (size_t)node * CS + off4);
        *(float4*)(&xl[nl * KP + slice * CS + off4]) = v;
    }

    int ct = tid & 31;
    int ng = tid >> 5;
    int c4 = ct * 4;
    float4 acc[4];
#pragma unroll
    for (int i = 0; i < 4; ++i) acc[i] = make_float4(0.f, 0.f, 0.f, 0.f);

    for (int p = 0; p < NPASS; ++p) {
        if (p > 0) __syncthreads();      // WAR on wl
        // stage W rows [p*KH, p*KH+KH) — coalesced float4 stream
        {
            const float4* Wsrc = (const float4*)(W + (size_t)p * KH * 128);
            float4* wl4 = (float4*)wl;
            for (int i = tid; i < KH * 32; i += 256) wl4[i] = Wsrc[i];
        }
        __syncthreads();                 // covers xl (p==0) + wl

        for (int k4 = 0; k4 < KH / 4; ++k4) {
            float4 wv0 = *(const float4*)(&wl[(k4 * 4 + 0) * 128 + c4]);
            float4 wv1 = *(const float4*)(&wl[(k4 * 4 + 1) * 128 + c4]);
            float4 wv2 = *(const float4*)(&wl[(k4 * 4 + 2) * 128 + c4]);
            float4 wv3 = *(const float4*)(&wl[(k4 * 4 + 3) * 128 + c4]);
#pragma unroll
            for (int i = 0; i < 4; ++i) {
                float4 xv = *(const float4*)(&xl[(ng * 4 + i) * KP + p * KH + k4 * 4]);
                acc[i].x += xv.x * wv0.x; acc[i].y += xv.x * wv0.y;
                acc[i].z += xv.x * wv0.z; acc[i].w += xv.x * wv0.w;
                acc[i].x += xv.y * wv1.x; acc[i].y += xv.y * wv1.y;
                acc[i].z += xv.y * wv1.z; acc[i].w += xv.y * wv1.w;
                acc[i].x += xv.z * wv2.x; acc[i].y += xv.z * wv2.y;
                acc[i].z += xv.z * wv2.z; acc[i].w += xv.z * wv2.w;
                acc[i].x += xv.w * wv3.x; acc[i].y += xv.w * wv3.y;
                acc[i].z += xv.w * wv3.z; acc[i].w += xv.w * wv3.w;
            }
        }
    }

    float4 ka = *(const float4*)(kA + c4);
    float4 kb = *(const float4*)(kB + c4);
#pragma unroll
    for (int i = 0; i < 4; ++i) {
        int node = base + ng * 4 + i;
        float4 a = acc[i];
        float4 v;
        v.x = fmaxf(a.x * ka.x + kb.x, 0.f);
        v.y = fmaxf(a.y * ka.y + kb.y, 0.f);
        v.z = fmaxf(a.z * ka.z + kb.z, 0.f);
        v.w = fmaxf(a.w * ka.w + kb.w, 0.f);
        if (POOL) {
            if (node < n) {
                float4 rv = *(const float4*)(res + (size_t)(c4 >> 4) * ((size_t)n * 16) +
                                             (size_t)node * 16 + (c4 & 15));
                v.x += rv.x; v.y += rv.y; v.z += rv.z; v.w += rv.w;
            }
        }
        acc[i] = v;
    }

    if (POOL) {
        __syncthreads();   // reuse xl as pool buffer
        int g0 = batch[base];
        int glast = batch[(base + 31 < n) ? (base + 31) : (n - 1)];
        int span = glast - g0 + 1;
        constexpr int MAXSPAN = 32 * KP / 128;
        if (span <= MAXSPAN) {
            float* pl = xl;
            for (int idx = tid; idx < span * 128; idx += 256) pl[idx] = 0.f;
            __syncthreads();
#pragma unroll
            for (int i = 0; i < 4; ++i) {
                int node = base + ng * 4 + i;
                if (node < n) {
                    int g = batch[node] - g0;
                    float* p = pl + g * 128 + c4;
                    atomicAdd(p + 0, acc[i].x);
                    atomicAdd(p + 1, acc[i].y);
                    atomicAdd(p + 2, acc[i].z);
                    atomicAdd(p + 3, acc[i].w);
                }
            }
            __syncthreads();
            for (int idx = tid; idx < span * 128; idx += 256)
                atomicAdd(&pooled[g0 * 128 + idx], pl[idx]);
        } else {
#pragma unroll
            for (int i = 0; i < 4; ++i) {
                int node = base + ng * 4 + i;
                if (node < n) {
                    float* p = pooled + (size_t)batch[node] * 128 + c4;
                    atomicAdd(p + 0, acc[i].x);
                    atomicAdd(p + 1, acc[i].y);
                    atomicAdd(p + 2, acc[i].z);
                    atomicAdd(p + 3, acc[i].w);
                }
            }
        }
    } else {
#pragma unroll
        for (int i = 0; i < 4; ++i) {
            int node = base + ng * 4 + i;
            if (node < n)
                *(float4*)(outs + (size_t)(c4 >> 4) * ((size_t)n * 16) +
                           (size_t)node * 16 + (c4 & 15)) = acc[i];
        }
    }
}

__global__ void k_final(const float* __restrict__ pooled, const float* __restrict__ gcnt,
                        const float* __restrict__ Wf, const float* __restrict__ bf,
                        float* __restrict__ out, int G) {
    int g = blockIdx.x * blockDim.x + threadIdx.x;
    if (g >= G) return;
    float s = 0.f;
    for (int c = 0; c < 128; ++c) s += pooled[g * 128 + c] * Wf[c];
    out[g] = s / fmaxf(gcnt[g], 1.0f) + bf[0];
}

// ---------------------------------------------------------------------------
extern "C" void kernel_launch(void* const* d_in, const int* in_sizes, int n_in,
                              void* d_out, int out_size, void* d_ws, size_t ws_size,
                              hipStream_t stream) {
    const float* x     = (const float*)d_in[0];
    const int*   ei    = (const int*)d_in[1];
    const int*   src   = ei;
    const int*   dst   = ei + N_EDGES;
    const float* w     = (const float*)d_in[2];
    const int*   batch = (const int*)d_in[3];
    const float* W1 = (const float*)d_in[4];
    const float* b1 = (const float*)d_in[5];
    const float* W2 = (const float*)d_in[6];
    const float* b2 = (const float*)d_in[7];
    const float* W3 = (const float*)d_in[8];
    const float* b3 = (const float*)d_in[9];
    const float* Wf = (const float*)d_in[10];
    const float* bf = (const float*)d_in[11];
    const float* g1 = (const float*)d_in[12];
    const float* be1 = (const float*)d_in[13];
    const float* m1 = (const float*)d_in[14];
    const float* v1 = (const float*)d_in[15];
    const float* g2 = (const float*)d_in[16];
    const float* be2 = (const float*)d_in[17];
    const float* m2 = (const float*)d_in[18];
    const float* v2 = (const float*)d_in[19];
    const float* g3 = (const float*)d_in[20];
    const float* be3 = (const float*)d_in[21];
    const float* m3 = (const float*)d_in[22];
    const float* v3 = (const float*)d_in[23];

    float* out = (float*)d_out;

    // Workspace layout (all sections 16B-aligned)
    float* ws    = (float*)d_ws;
    float* out2s = ws;                                    // N*128 sliced-16 (layer-2 out / res)
    float* buf2  = out2s + (size_t)N_NODES * 128;         // N*128: agg2 (N*64) then agg3s
    float* agg2  = buf2;                                  // plain [node][64]
    int2*  csr   = (int2*)(buf2 + (size_t)N_NODES * 128); // E
    float* wdeg  = (float*)(csr + N_EDGES);               // N (becomes dinv)
    int*   cnt_i = (int*)(wdeg + N_NODES);                // N
    int*   cursor = cnt_i + N_NODES;                      // N (reused as aggx)
    float* aggx  = (float*)cursor;
    float* kA1   = (float*)(cursor + N_NODES);            // 64
    float* kB1   = kA1 + 64;                              // 64
    float* kA2   = kB1 + 64;                              // 128
    float* kB2   = kA2 + 128;                             // 128
    float* kA3   = kB2 + 128;                             // 128
    float* kB3   = kA3 + 128;                             // 128
    float* pooled = kB3 + 128;                            // G*128
    float* gcnt  = pooled + (size_t)N_GRAPHS * 128;       // G
    int*   offs  = (int*)(gcnt + N_GRAPHS);               // N+1
    int*   bsum  = offs + N_NODES + 1;                    // SCAN_NB
    int*   bpre  = bsum + SCAN_NB;                        // SCAN_NB

    const int BS = 256;
    auto nb = [](long n) { return (int)((n + 255) / 256); };

    hipMemsetAsync(wdeg, 0, N_NODES * sizeof(float), stream);
    hipMemsetAsync(cnt_i, 0, N_NODES * sizeof(int), stream);
    hipMemsetAsync(pooled, 0, (size_t)N_GRAPHS * 129 * sizeof(float), stream);

    // --- CSR build + degree norm ---
    k_degcnt<<<nb(N_EDGES), BS, 0, stream>>>(dst, w, wdeg, cnt_i, N_EDGES);
    k_scan1<<<SCAN_NB, 256, 0, stream>>>(cnt_i, bsum, N_NODES);
    k_scan2<<<1, 256, 0, stream>>>(bsum, bpre, SCAN_NB);
    k_scan3<<<SCAN_NB, 256, 0, stream>>>(cnt_i, bpre, offs, cursor, N_NODES);
    k_dinv_gcnt<<<nb(N_NODES), BS, 0, stream>>>(wdeg, batch, gcnt, N_NODES);
    float* dinv = wdeg;
    k_fill<<<nb(N_EDGES), BS, 0, stream>>>(src, dst, w, dinv, cursor, csr, N_EDGES);
    k_bnprep_all<<<1, 320, 0, stream>>>(W1, b1, g1, be1, m1, v1, b2, g2, be2, m2, v2,
                                        b3, g3, be3, m3, v3, kA1, kB1, kA2, kB2, kA3, kB3);

    // --- Layer 1 aggregate (scalar) ---
    k_aggx<<<nb(N_NODES), BS, 0, stream>>>(offs, csr, x, dinv, aggx, N_NODES);

    // --- Layer 2: fused L1-matmul + aggregate, then 64->128 matmul ---
    k_gather2F<<<nb((long)N_NODES * 16), BS, 0, stream>>>(
        offs, csr, aggx, dinv, kA1, kB1, agg2, N_NODES);
    k_mmT<64, 1, false><<<(N_NODES + 31) / 32, BS, 0, stream>>>(
        agg2, W2, kA2, kB2, nullptr, nullptr, out2s, nullptr, N_NODES);

    // --- Layer 3: sliced aggregate, then 128->128 matmul + res + pool ---
    k_gatherS16<<<8 * ((N_NODES + 63) / 64), BS, 0, stream>>>(
        offs, csr, out2s, dinv, buf2, N_NODES);
    k_mmT<128, 8, true><<<(N_NODES + 31) / 32, BS, 0, stream>>>(
        buf2, W3, kA3, kB3, out2s, batch, nullptr, pooled, N_NODES);

    // --- final linear ---
    k_final<<<nb(N_GRAPHS), BS, 0, stream>>>(pooled, gcnt, Wf, bf, out, N_GRAPHS);
}

// Round 9
// 443.483 us; speedup vs baseline: 2.1151x; 2.1151x over previous
//
#include <hip/hip_runtime.h>

#define N_NODES  50000
#define N_EDGES  640000
#define N_GRAPHS 500
static constexpr float BN_EPS = 1e-5f;
#define SCAN_NB ((N_NODES + 255) / 256)   // 196 blocks

// ---------------------------------------------------------------------------
__global__ void k_degcnt(const int* __restrict__ dst, const float* __restrict__ w,
                         float* __restrict__ wdeg, int* __restrict__ cnt, int E) {
    int i = blockIdx.x * blockDim.x + threadIdx.x;
    if (i < E) {
        int d = dst[i];
        atomicAdd(&wdeg[d], w[i]);
        atomicAdd(&cnt[d], 1);
    }
}

__global__ void k_dinv_gcnt(float* __restrict__ wdeg, const int* __restrict__ batch,
                            float* __restrict__ gcnt, int n) {
    int i = blockIdx.x * blockDim.x + threadIdx.x;
    if (i < n) {
        wdeg[i] = rsqrtf(wdeg[i] + 1.0f);
        atomicAdd(&gcnt[batch[i]], 1.0f);
    }
}

// --- 3-phase hierarchical exclusive scan of cnt[N] -> offs[N+1] (+cursor) ---
__global__ void k_scan1(const int* __restrict__ cnt, int* __restrict__ bsum, int n) {
    __shared__ int red[256];
    int i = blockIdx.x * 256 + threadIdx.x;
    red[threadIdx.x] = (i < n) ? cnt[i] : 0;
    __syncthreads();
    for (int off = 128; off > 0; off >>= 1) {
        if (threadIdx.x < off) red[threadIdx.x] += red[threadIdx.x + off];
        __syncthreads();
    }
    if (threadIdx.x == 0) bsum[blockIdx.x] = red[0];
}

__global__ void k_scan2(const int* __restrict__ bsum, int* __restrict__ bpre, int nb) {
    __shared__ int part[256];
    int t = threadIdx.x;
    part[t] = (t < nb) ? bsum[t] : 0;
    __syncthreads();
    for (int off = 1; off < 256; off <<= 1) {
        int v = (t >= off) ? part[t - off] : 0;
        __syncthreads();
        part[t] += v;
        __syncthreads();
    }
    if (t < nb) bpre[t] = (t == 0) ? 0 : part[t - 1];
}

__global__ void k_scan3(const int* __restrict__ cnt, const int* __restrict__ bpre,
                        int* __restrict__ offs, int* __restrict__ cursor, int n) {
    __shared__ int part[256];
    int i = blockIdx.x * 256 + threadIdx.x;
    int t = threadIdx.x;
    int v = (i < n) ? cnt[i] : 0;
    part[t] = v;
    __syncthreads();
    for (int off = 1; off < 256; off <<= 1) {
        int u = (t >= off) ? part[t - off] : 0;
        __syncthreads();
        part[t] += u;
        __syncthreads();
    }
    int excl = bpre[blockIdx.x] + part[t] - v;
    if (i < n) {
        offs[i] = excl;
        cursor[i] = excl;
    }
    if (i == n - 1) offs[n] = N_EDGES;
}

__global__ void k_fill(const int* __restrict__ src, const int* __restrict__ dst,
                       const float* __restrict__ w, const float* __restrict__ dinv,
                       int* __restrict__ cursor, int2* __restrict__ csr, int E) {
    int e = blockIdx.x * blockDim.x + threadIdx.x;
    if (e < E) {
        int s = src[e], d = dst[e];
        int pos = atomicAdd(&cursor[d], 1);
        csr[pos] = make_int2(s, __float_as_int(dinv[s] * w[e] * dinv[d]));
    }
}

// Fold bias+BN into per-channel affine. Layer1 additionally folds W1 (rank-1).
__global__ void k_bnprep_all(
    const float* W1,
    const float* b1, const float* g1, const float* be1, const float* m1, const float* v1,
    const float* b2, const float* g2, const float* be2, const float* m2, const float* v2,
    const float* b3, const float* g3, const float* be3, const float* m3, const float* v3,
    float* kA1, float* kB1, float* kA2, float* kB2, float* kA3, float* kB3) {
    int t = threadIdx.x;
    if (t < 64) {
        float s = g1[t] * rsqrtf(v1[t] + BN_EPS);
        kA1[t] = W1[t] * s;
        kB1[t] = (b1[t] - m1[t]) * s + be1[t];
    } else if (t < 192) {
        int c = t - 64;
        float s = g2[c] * rsqrtf(v2[c] + BN_EPS);
        kA2[c] = s; kB2[c] = (b2[c] - m2[c]) * s + be2[c];
    } else if (t < 320) {
        int c = t - 192;
        float s = g3[c] * rsqrtf(v3[c] + BN_EPS);
        kA3[c] = s; kB3[c] = (b3[c] - m3[c]) * s + be3[c];
    }
}

// Layer-1 scalar aggregation over the 200KB x table.
__global__ void k_aggx(const int* __restrict__ offs, const int2* __restrict__ csr,
                       const float* __restrict__ x, const float* __restrict__ dinv,
                       float* __restrict__ aggx, int n) {
    int i = blockIdx.x * blockDim.x + threadIdx.x;
    if (i >= n) return;
    float acc = 0.f;
    int e0 = offs[i], e1 = offs[i + 1];
    for (int j = e0; j < e1; ++j) {
        int2 e = csr[j];
        acc += x[e.x] * __int_as_float(e.y);
    }
    float di = dinv[i];
    aggx[i] = acc + x[i] * di * di;
}

// ---------------------------------------------------------------------------
// Fused layer-1-matmul + layer-2 aggregation.
__global__ void k_gather2F(const int* __restrict__ offs, const int2* __restrict__ csr,
                           const float* __restrict__ aggx, const float* __restrict__ dinv,
                           const float* __restrict__ kA1, const float* __restrict__ kB1,
                           float* __restrict__ agg2, int n) {
    int gid = blockIdx.x * blockDim.x + threadIdx.x;
    int node = gid >> 4;
    if (node >= n) return;
    int c4 = (gid & 15) * 4;
    float4 wa = *(const float4*)(kA1 + c4);
    float4 wb = *(const float4*)(kB1 + c4);
    float4 acc = {0.f, 0.f, 0.f, 0.f};
    int e0 = offs[node], e1 = offs[node + 1];
    for (int j = e0; j < e1; ++j) {
        int2 e = csr[j];
        float a = aggx[e.x];
        float nm = __int_as_float(e.y);
        acc.x += nm * fmaxf(a * wa.x + wb.x, 0.f);
        acc.y += nm * fmaxf(a * wa.y + wb.y, 0.f);
        acc.z += nm * fmaxf(a * wa.z + wb.z, 0.f);
        acc.w += nm * fmaxf(a * wa.w + wb.w, 0.f);
    }
    float di = dinv[node];
    float d2 = di * di;
    float a = aggx[node];
    acc.x += d2 * fmaxf(a * wa.x + wb.x, 0.f);
    acc.y += d2 * fmaxf(a * wa.y + wb.y, 0.f);
    acc.z += d2 * fmaxf(a * wa.z + wb.z, 0.f);
    acc.w += d2 * fmaxf(a * wa.w + wb.w, 0.f);
    *(float4*)(agg2 + (size_t)node * 64 + c4) = acc;
}

// ---------------------------------------------------------------------------
// Channel-sliced gather (layer 3): slice = blockIdx%8 -> XCD-local 3.2MB table.
__global__ void k_gatherS16(const int* __restrict__ offs, const int2* __restrict__ csr,
                            const float* __restrict__ Hs, const float* __restrict__ dinv,
                            float* __restrict__ aggs, int n) {
    int slice = blockIdx.x & 7;
    int node = (blockIdx.x >> 3) * 64 + threadIdx.x / 4;
    if (node >= n) return;
    int cq = (threadIdx.x % 4) * 4;
    const float* Hb = Hs + (size_t)slice * ((size_t)n * 16);
    float4 acc = {0.f, 0.f, 0.f, 0.f};
    int e0 = offs[node], e1 = offs[node + 1];
    for (int j = e0; j < e1; ++j) {
        int2 e = csr[j];
        float nm = __int_as_float(e.y);
        float4 hv = *(const float4*)(Hb + (size_t)e.x * 16 + cq);
        acc.x += hv.x * nm;
        acc.y += hv.y * nm;
        acc.z += hv.z * nm;
        acc.w += hv.w * nm;
    }
    float di = dinv[node];
    float d2 = di * di;
    float4 hv = *(const float4*)(Hb + (size_t)node * 16 + cq);
    acc.x += hv.x * d2;
    acc.y += hv.y * d2;
    acc.z += hv.z * d2;
    acc.w += hv.w * d2;
    *(float4*)(aggs + (size_t)slice * ((size_t)n * 16) + (size_t)node * 16 + cq) = acc;
}

// ---------------------------------------------------------------------------
// Register-tiled matmul: 32 nodes/block, x-tile AND W staged in LDS.
// Hot K-loop touches LDS only. CRITICAL: k4/p loops pinned rolled with
// `#pragma unroll 1` — rounds 6 & 8 both spilled to 256 VGPR (FETCH 26->800MB)
// when the compiler fully unrolled a load loop and batched all loads.
template <int K, int S, bool POOL>
__global__ __launch_bounds__(256) void k_mmT(
    const float* __restrict__ Xs, const float* __restrict__ W,
    const float* __restrict__ kA, const float* __restrict__ kB,
    const float* __restrict__ res, const int* __restrict__ batch,
    float* __restrict__ outs, float* __restrict__ pooled, int n) {
    constexpr int CS = K / S;
    constexpr int KP = K + 4;            // padded LDS row stride (floats)
    constexpr int KH = 64;               // W half-pass rows
    constexpr int NPASS = K / KH;
    __shared__ float xl[32 * KP];
    __shared__ float wl[KH * 128];       // 32 KB
    int base = blockIdx.x * 32;
    int tid = threadIdx.x;
    constexpr int TOT4 = 32 * K / 4;
    constexpr int SL4 = 32 * CS / 4;
    for (int i = tid; i < TOT4; i += 256) {
        int slice = i / SL4;
        int rem = i - slice * SL4;
        int nl = rem / (CS / 4);
        int off4 = (rem % (CS / 4)) * 4;
        int node = base + nl;
        float4 v = {0.f, 0.f, 0.f, 0.f};
        if (node < n)
            v = *(const float4*)(Xs + (size_t)slice * ((size_t)n * CS) + (size_t)node * CS + off4);
        *(float4*)(&xl[nl * KP + slice * CS + off4]) = v;
    }

    int ct = tid & 31;
    int ng = tid >> 5;
    int c4 = ct * 4;
    float4 acc[4];
#pragma unroll
    for (int i = 0; i < 4; ++i) acc[i] = make_float4(0.f, 0.f, 0.f, 0.f);

#pragma unroll 1
    for (int p = 0; p < NPASS; ++p) {
        if (p > 0) __syncthreads();      // WAR on wl
        // stage W rows [p*KH, p*KH+KH) — coalesced float4 stream
        {
            const float4* Wsrc = (const float4*)(W + (size_t)p * KH * 128);
            float4* wl4 = (float4*)wl;
#pragma unroll 1
            for (int i = tid; i < KH * 32; i += 256) wl4[i] = Wsrc[i];
        }
        __syncthreads();                 // covers xl (p==0) + wl

#pragma unroll 1
        for (int k4 = 0; k4 < KH / 4; ++k4) {
            float4 wv0 = *(const float4*)(&wl[(k4 * 4 + 0) * 128 + c4]);
            float4 wv1 = *(const float4*)(&wl[(k4 * 4 + 1) * 128 + c4]);
            float4 wv2 = *(const float4*)(&wl[(k4 * 4 + 2) * 128 + c4]);
            float4 wv3 = *(const float4*)(&wl[(k4 * 4 + 3) * 128 + c4]);
#pragma unroll
            for (int i = 0; i < 4; ++i) {
                float4 xv = *(const float4*)(&xl[(ng * 4 + i) * KP + p * KH + k4 * 4]);
                acc[i].x += xv.x * wv0.x; acc[i].y += xv.x * wv0.y;
                acc[i].z += xv.x * wv0.z; acc[i].w += xv.x * wv0.w;
                acc[i].x += xv.y * wv1.x; acc[i].y += xv.y * wv1.y;
                acc[i].z += xv.y * wv1.z; acc[i].w += xv.y * wv1.w;
                acc[i].x += xv.z * wv2.x; acc[i].y += xv.z * wv2.y;
                acc[i].z += xv.z * wv2.z; acc[i].w += xv.z * wv2.w;
                acc[i].x += xv.w * wv3.x; acc[i].y += xv.w * wv3.y;
                acc[i].z += xv.w * wv3.z; acc[i].w += xv.w * wv3.w;
            }
        }
    }

    float4 ka = *(const float4*)(kA + c4);
    float4 kb = *(const float4*)(kB + c4);
#pragma unroll
    for (int i = 0; i < 4; ++i) {
        int node = base + ng * 4 + i;
        float4 a = acc[i];
        float4 v;
        v.x = fmaxf(a.x * ka.x + kb.x, 0.f);
        v.y = fmaxf(a.y * ka.y + kb.y, 0.f);
        v.z = fmaxf(a.z * ka.z + kb.z, 0.f);
        v.w = fmaxf(a.w * ka.w + kb.w, 0.f);
        if (POOL) {
            if (node < n) {
                float4 rv = *(const float4*)(res + (size_t)(c4 >> 4) * ((size_t)n * 16) +
                                             (size_t)node * 16 + (c4 & 15));
                v.x += rv.x; v.y += rv.y; v.z += rv.z; v.w += rv.w;
            }
        }
        acc[i] = v;
    }

    if (POOL) {
        __syncthreads();   // reuse xl as pool buffer
        int g0 = batch[base];
        int glast = batch[(base + 31 < n) ? (base + 31) : (n - 1)];
        int span = glast - g0 + 1;
        constexpr int MAXSPAN = 32 * KP / 128;
        if (span <= MAXSPAN) {
            float* pl = xl;
            for (int idx = tid; idx < span * 128; idx += 256) pl[idx] = 0.f;
            __syncthreads();
#pragma unroll
            for (int i = 0; i < 4; ++i) {
                int node = base + ng * 4 + i;
                if (node < n) {
                    int g = batch[node] - g0;
                    float* p = pl + g * 128 + c4;
                    atomicAdd(p + 0, acc[i].x);
                    atomicAdd(p + 1, acc[i].y);
                    atomicAdd(p + 2, acc[i].z);
                    atomicAdd(p + 3, acc[i].w);
                }
            }
            __syncthreads();
            for (int idx = tid; idx < span * 128; idx += 256)
                atomicAdd(&pooled[g0 * 128 + idx], pl[idx]);
        } else {
#pragma unroll
            for (int i = 0; i < 4; ++i) {
                int node = base + ng * 4 + i;
                if (node < n) {
                    float* p = pooled + (size_t)batch[node] * 128 + c4;
                    atomicAdd(p + 0, acc[i].x);
                    atomicAdd(p + 1, acc[i].y);
                    atomicAdd(p + 2, acc[i].z);
                    atomicAdd(p + 3, acc[i].w);
                }
            }
        }
    } else {
#pragma unroll
        for (int i = 0; i < 4; ++i) {
            int node = base + ng * 4 + i;
            if (node < n)
                *(float4*)(outs + (size_t)(c4 >> 4) * ((size_t)n * 16) +
                           (size_t)node * 16 + (c4 & 15)) = acc[i];
        }
    }
}

__global__ void k_final(const float* __restrict__ pooled, const float* __restrict__ gcnt,
                        const float* __restrict__ Wf, const float* __restrict__ bf,
                        float* __restrict__ out, int G) {
    int g = blockIdx.x * blockDim.x + threadIdx.x;
    if (g >= G) return;
    float s = 0.f;
    for (int c = 0; c < 128; ++c) s += pooled[g * 128 + c] * Wf[c];
    out[g] = s / fmaxf(gcnt[g], 1.0f) + bf[0];
}

// ---------------------------------------------------------------------------
extern "C" void kernel_launch(void* const* d_in, const int* in_sizes, int n_in,
                              void* d_out, int out_size, void* d_ws, size_t ws_size,
                              hipStream_t stream) {
    const float* x     = (const float*)d_in[0];
    const int*   ei    = (const int*)d_in[1];
    const int*   src   = ei;
    const int*   dst   = ei + N_EDGES;
    const float* w     = (const float*)d_in[2];
    const int*   batch = (const int*)d_in[3];
    const float* W1 = (const float*)d_in[4];
    const float* b1 = (const float*)d_in[5];
    const float* W2 = (const float*)d_in[6];
    const float* b2 = (const float*)d_in[7];
    const float* W3 = (const float*)d_in[8];
    const float* b3 = (const float*)d_in[9];
    const float* Wf = (const float*)d_in[10];
    const float* bf = (const float*)d_in[11];
    const float* g1 = (const float*)d_in[12];
    const float* be1 = (const float*)d_in[13];
    const float* m1 = (const float*)d_in[14];
    const float* v1 = (const float*)d_in[15];
    const float* g2 = (const float*)d_in[16];
    const float* be2 = (const float*)d_in[17];
    const float* m2 = (const float*)d_in[18];
    const float* v2 = (const float*)d_in[19];
    const float* g3 = (const float*)d_in[20];
    const float* be3 = (const float*)d_in[21];
    const float* m3 = (const float*)d_in[22];
    const float* v3 = (const float*)d_in[23];

    float* out = (float*)d_out;

    // Workspace layout (all sections 16B-aligned)
    float* ws    = (float*)d_ws;
    float* out2s = ws;                                    // N*128 sliced-16 (layer-2 out / res)
    float* buf2  = out2s + (size_t)N_NODES * 128;         // N*128: agg2 (N*64) then agg3s
    float* agg2  = buf2;                                  // plain [node][64]
    int2*  csr   = (int2*)(buf2 + (size_t)N_NODES * 128); // E
    float* wdeg  = (float*)(csr + N_EDGES);               // N (becomes dinv)
    int*   cnt_i = (int*)(wdeg + N_NODES);                // N
    int*   cursor = cnt_i + N_NODES;                      // N (reused as aggx)
    float* aggx  = (float*)cursor;
    float* kA1   = (float*)(cursor + N_NODES);            // 64
    float* kB1   = kA1 + 64;                              // 64
    float* kA2   = kB1 + 64;                              // 128
    float* kB2   = kA2 + 128;                             // 128
    float* kA3   = kB2 + 128;                             // 128
    float* kB3   = kA3 + 128;                             // 128
    float* pooled = kB3 + 128;                            // G*128
    float* gcnt  = pooled + (size_t)N_GRAPHS * 128;       // G
    int*   offs  = (int*)(gcnt + N_GRAPHS);               // N+1
    int*   bsum  = offs + N_NODES + 1;                    // SCAN_NB
    int*   bpre  = bsum + SCAN_NB;                        // SCAN_NB

    const int BS = 256;
    auto nb = [](long n) { return (int)((n + 255) / 256); };

    hipMemsetAsync(wdeg, 0, N_NODES * sizeof(float), stream);
    hipMemsetAsync(cnt_i, 0, N_NODES * sizeof(int), stream);
    hipMemsetAsync(pooled, 0, (size_t)N_GRAPHS * 129 * sizeof(float), stream);

    // --- CSR build + degree norm ---
    k_degcnt<<<nb(N_EDGES), BS, 0, stream>>>(dst, w, wdeg, cnt_i, N_EDGES);
    k_scan1<<<SCAN_NB, 256, 0, stream>>>(cnt_i, bsum, N_NODES);
    k_scan2<<<1, 256, 0, stream>>>(bsum, bpre, SCAN_NB);
    k_scan3<<<SCAN_NB, 256, 0, stream>>>(cnt_i, bpre, offs, cursor, N_NODES);
    k_dinv_gcnt<<<nb(N_NODES), BS, 0, stream>>>(wdeg, batch, gcnt, N_NODES);
    float* dinv = wdeg;
    k_fill<<<nb(N_EDGES), BS, 0, stream>>>(src, dst, w, dinv, cursor, csr, N_EDGES);
    k_bnprep_all<<<1, 320, 0, stream>>>(W1, b1, g1, be1, m1, v1, b2, g2, be2, m2, v2,
                                        b3, g3, be3, m3, v3, kA1, kB1, kA2, kB2, kA3, kB3);

    // --- Layer 1 aggregate (scalar) ---
    k_aggx<<<nb(N_NODES), BS, 0, stream>>>(offs, csr, x, dinv, aggx, N_NODES);

    // --- Layer 2: fused L1-matmul + aggregate, then 64->128 matmul ---
    k_gather2F<<<nb((long)N_NODES * 16), BS, 0, stream>>>(
        offs, csr, aggx, dinv, kA1, kB1, agg2, N_NODES);
    k_mmT<64, 1, false><<<(N_NODES + 31) / 32, BS, 0, stream>>>(
        agg2, W2, kA2, kB2, nullptr, nullptr, out2s, nullptr, N_NODES);

    // --- Layer 3: sliced aggregate, then 128->128 matmul + res + pool ---
    k_gatherS16<<<8 * ((N_NODES + 63) / 64), BS, 0, stream>>>(
        offs, csr, out2s, dinv, buf2, N_NODES);
    k_mmT<128, 8, true><<<(N_NODES + 31) / 32, BS, 0, stream>>>(
        buf2, W3, kA3, kB3, out2s, batch, nullptr, pooled, N_NODES);

    // --- final linear ---
    k_final<<<nb(N_GRAPHS), BS, 0, stream>>>(pooled, gcnt, Wf, bf, out, N_GRAPHS);
}

// Round 10
// 394.065 us; speedup vs baseline: 2.3803x; 1.1254x over previous
//
#include <hip/hip_runtime.h>

#define N_NODES  50000
#define N_EDGES  640000
#define N_GRAPHS 500
static constexpr float BN_EPS = 1e-5f;
#define SCAN_NB ((N_NODES + 255) / 256)   // 196 blocks

// ---------------------------------------------------------------------------
__global__ void k_degcnt(const int* __restrict__ dst, const float* __restrict__ w,
                         float* __restrict__ wdeg, int* __restrict__ cnt, int E) {
    int i = blockIdx.x * blockDim.x + threadIdx.x;
    if (i < E) {
        int d = dst[i];
        atomicAdd(&wdeg[d], w[i]);
        atomicAdd(&cnt[d], 1);
    }
}

__global__ void k_dinv(float* __restrict__ wdeg, int n) {
    int i = blockIdx.x * blockDim.x + threadIdx.x;
    if (i < n) wdeg[i] = rsqrtf(wdeg[i] + 1.0f);
}

// --- 3-phase hierarchical exclusive scan of cnt[N] -> offs[N+1] (+cursor) ---
__global__ void k_scan1(const int* __restrict__ cnt, int* __restrict__ bsum, int n) {
    __shared__ int red[256];
    int i = blockIdx.x * 256 + threadIdx.x;
    red[threadIdx.x] = (i < n) ? cnt[i] : 0;
    __syncthreads();
    for (int off = 128; off > 0; off >>= 1) {
        if (threadIdx.x < off) red[threadIdx.x] += red[threadIdx.x + off];
        __syncthreads();
    }
    if (threadIdx.x == 0) bsum[blockIdx.x] = red[0];
}

__global__ void k_scan2(const int* __restrict__ bsum, int* __restrict__ bpre, int nb) {
    __shared__ int part[256];
    int t = threadIdx.x;
    part[t] = (t < nb) ? bsum[t] : 0;
    __syncthreads();
    for (int off = 1; off < 256; off <<= 1) {
        int v = (t >= off) ? part[t - off] : 0;
        __syncthreads();
        part[t] += v;
        __syncthreads();
    }
    if (t < nb) bpre[t] = (t == 0) ? 0 : part[t - 1];
}

__global__ void k_scan3(const int* __restrict__ cnt, const int* __restrict__ bpre,
                        int* __restrict__ offs, int* __restrict__ cursor, int n) {
    __shared__ int part[256];
    int i = blockIdx.x * 256 + threadIdx.x;
    int t = threadIdx.x;
    int v = (i < n) ? cnt[i] : 0;
    part[t] = v;
    __syncthreads();
    for (int off = 1; off < 256; off <<= 1) {
        int u = (t >= off) ? part[t - off] : 0;
        __syncthreads();
        part[t] += u;
        __syncthreads();
    }
    int excl = bpre[blockIdx.x] + part[t] - v;
    if (i < n) {
        offs[i] = excl;
        cursor[i] = excl;
    }
    if (i == n - 1) offs[n] = N_EDGES;
}

__global__ void k_fill(const int* __restrict__ src, const int* __restrict__ dst,
                       const float* __restrict__ w, const float* __restrict__ dinv,
                       int* __restrict__ cursor, int2* __restrict__ csr, int E) {
    int e = blockIdx.x * blockDim.x + threadIdx.x;
    if (e < E) {
        int s = src[e], d = dst[e];
        int pos = atomicAdd(&cursor[d], 1);
        csr[pos] = make_int2(s, __float_as_int(dinv[s] * w[e] * dinv[d]));
    }
}

// Fold bias+BN into per-channel affine. Layer1 additionally folds W1 (rank-1).
__global__ void k_bnprep_all(
    const float* W1,
    const float* b1, const float* g1, const float* be1, const float* m1, const float* v1,
    const float* b2, const float* g2, const float* be2, const float* m2, const float* v2,
    const float* b3, const float* g3, const float* be3, const float* m3, const float* v3,
    float* kA1, float* kB1, float* kA2, float* kB2, float* kA3, float* kB3) {
    int t = threadIdx.x;
    if (t < 64) {
        float s = g1[t] * rsqrtf(v1[t] + BN_EPS);
        kA1[t] = W1[t] * s;
        kB1[t] = (b1[t] - m1[t]) * s + be1[t];
    } else if (t < 192) {
        int c = t - 64;
        float s = g2[c] * rsqrtf(v2[c] + BN_EPS);
        kA2[c] = s; kB2[c] = (b2[c] - m2[c]) * s + be2[c];
    } else if (t < 320) {
        int c = t - 192;
        float s = g3[c] * rsqrtf(v3[c] + BN_EPS);
        kA3[c] = s; kB3[c] = (b3[c] - m3[c]) * s + be3[c];
    }
}

// Layer-1 scalar aggregation over the 200KB x table.
__global__ void k_aggx(const int* __restrict__ offs, const int2* __restrict__ csr,
                       const float* __restrict__ x, const float* __restrict__ dinv,
                       float* __restrict__ aggx, int n) {
    int i = blockIdx.x * blockDim.x + threadIdx.x;
    if (i >= n) return;
    float acc = 0.f;
    int e0 = offs[i], e1 = offs[i + 1];
    for (int j = e0; j < e1; ++j) {
        int2 e = csr[j];
        acc += x[e.x] * __int_as_float(e.y);
    }
    float di = dinv[i];
    aggx[i] = acc + x[i] * di * di;
}

// ---------------------------------------------------------------------------
// Fused layer-1-matmul + layer-2 aggregation.
__global__ void k_gather2F(const int* __restrict__ offs, const int2* __restrict__ csr,
                           const float* __restrict__ aggx, const float* __restrict__ dinv,
                           const float* __restrict__ kA1, const float* __restrict__ kB1,
                           float* __restrict__ agg2, int n) {
    int gid = blockIdx.x * blockDim.x + threadIdx.x;
    int node = gid >> 4;
    if (node >= n) return;
    int c4 = (gid & 15) * 4;
    float4 wa = *(const float4*)(kA1 + c4);
    float4 wb = *(const float4*)(kB1 + c4);
    float4 acc = {0.f, 0.f, 0.f, 0.f};
    int e0 = offs[node], e1 = offs[node + 1];
    for (int j = e0; j < e1; ++j) {
        int2 e = csr[j];
        float a = aggx[e.x];
        float nm = __int_as_float(e.y);
        acc.x += nm * fmaxf(a * wa.x + wb.x, 0.f);
        acc.y += nm * fmaxf(a * wa.y + wb.y, 0.f);
        acc.z += nm * fmaxf(a * wa.z + wb.z, 0.f);
        acc.w += nm * fmaxf(a * wa.w + wb.w, 0.f);
    }
    float di = dinv[node];
    float d2 = di * di;
    float a = aggx[node];
    acc.x += d2 * fmaxf(a * wa.x + wb.x, 0.f);
    acc.y += d2 * fmaxf(a * wa.y + wb.y, 0.f);
    acc.z += d2 * fmaxf(a * wa.z + wb.z, 0.f);
    acc.w += d2 * fmaxf(a * wa.w + wb.w, 0.f);
    *(float4*)(agg2 + (size_t)node * 64 + c4) = acc;
}

// ---------------------------------------------------------------------------
// Channel-sliced gather (layer 3): slice = blockIdx%8 -> XCD-local 3.2MB table.
__global__ void k_gatherS16(const int* __restrict__ offs, const int2* __restrict__ csr,
                            const float* __restrict__ Hs, const float* __restrict__ dinv,
                            float* __restrict__ aggs, int n) {
    int slice = blockIdx.x & 7;
    int node = (blockIdx.x >> 3) * 64 + threadIdx.x / 4;
    if (node >= n) return;
    int cq = (threadIdx.x % 4) * 4;
    const float* Hb = Hs + (size_t)slice * ((size_t)n * 16);
    float4 acc = {0.f, 0.f, 0.f, 0.f};
    int e0 = offs[node], e1 = offs[node + 1];
    for (int j = e0; j < e1; ++j) {
        int2 e = csr[j];
        float nm = __int_as_float(e.y);
        float4 hv = *(const float4*)(Hb + (size_t)e.x * 16 + cq);
        acc.x += hv.x * nm;
        acc.y += hv.y * nm;
        acc.z += hv.z * nm;
        acc.w += hv.w * nm;
    }
    float di = dinv[node];
    float d2 = di * di;
    float4 hv = *(const float4*)(Hb + (size_t)node * 16 + cq);
    acc.x += hv.x * d2;
    acc.y += hv.y * d2;
    acc.z += hv.z * d2;
    acc.w += hv.w * d2;
    *(float4*)(aggs + (size_t)slice * ((size_t)n * 16) + (size_t)node * 16 + cq) = acc;
}

// ---------------------------------------------------------------------------
// Register-tiled matmul: 32 nodes/block, x-tile AND W staged in LDS.
// k4/p loops pinned rolled (#pragma unroll 1) — r6/r8 spilled at 256 VGPR when
// the compiler unrolled a load loop. NO pooling epilogue (r9 isolation test):
// RES=true adds residual read from `res` and writes IN-PLACE to the same
// sliced slot (outs may alias res — each slot owned by exactly one thread).
template <int K, int S, bool RES>
__global__ __launch_bounds__(256) void k_mmT(
    const float* __restrict__ Xs, const float* __restrict__ W,
    const float* __restrict__ kA, const float* __restrict__ kB,
    const float* __restrict__ res, float* __restrict__ outs, int n) {
    constexpr int CS = K / S;
    constexpr int KP = K + 4;            // padded LDS row stride (floats)
    constexpr int KH = 64;               // W half-pass rows
    constexpr int NPASS = K / KH;
    __shared__ float xl[32 * KP];
    __shared__ float wl[KH * 128];       // 32 KB
    int base = blockIdx.x * 32;
    int tid = threadIdx.x;
    constexpr int TOT4 = 32 * K / 4;
    constexpr int SL4 = 32 * CS / 4;
    for (int i = tid; i < TOT4; i += 256) {
        int slice = i / SL4;
        int rem = i - slice * SL4;
        int nl = rem / (CS / 4);
        int off4 = (rem % (CS / 4)) * 4;
        int node = base + nl;
        float4 v = {0.f, 0.f, 0.f, 0.f};
        if (node < n)
            v = *(const float4*)(Xs + (size_t)slice * ((size_t)n * CS) + (size_t)node * CS + off4);
        *(float4*)(&xl[nl * KP + slice * CS + off4]) = v;
    }

    int ct = tid & 31;
    int ng = tid >> 5;
    int c4 = ct * 4;
    float4 acc[4];
#pragma unroll
    for (int i = 0; i < 4; ++i) acc[i] = make_float4(0.f, 0.f, 0.f, 0.f);

#pragma unroll 1
    for (int p = 0; p < NPASS; ++p) {
        if (p > 0) __syncthreads();      // WAR on wl
        {
            const float4* Wsrc = (const float4*)(W + (size_t)p * KH * 128);
            float4* wl4 = (float4*)wl;
#pragma unroll 1
            for (int i = tid; i < KH * 32; i += 256) wl4[i] = Wsrc[i];
        }
        __syncthreads();                 // covers xl (p==0) + wl

#pragma unroll 1
        for (int k4 = 0; k4 < KH / 4; ++k4) {
            float4 wv0 = *(const float4*)(&wl[(k4 * 4 + 0) * 128 + c4]);
            float4 wv1 = *(const float4*)(&wl[(k4 * 4 + 1) * 128 + c4]);
            float4 wv2 = *(const float4*)(&wl[(k4 * 4 + 2) * 128 + c4]);
            float4 wv3 = *(const float4*)(&wl[(k4 * 4 + 3) * 128 + c4]);
#pragma unroll
            for (int i = 0; i < 4; ++i) {
                float4 xv = *(const float4*)(&xl[(ng * 4 + i) * KP + p * KH + k4 * 4]);
                acc[i].x += xv.x * wv0.x; acc[i].y += xv.x * wv0.y;
                acc[i].z += xv.x * wv0.z; acc[i].w += xv.x * wv0.w;
                acc[i].x += xv.y * wv1.x; acc[i].y += xv.y * wv1.y;
                acc[i].z += xv.y * wv1.z; acc[i].w += xv.y * wv1.w;
                acc[i].x += xv.z * wv2.x; acc[i].y += xv.z * wv2.y;
                acc[i].z += xv.z * wv2.z; acc[i].w += xv.z * wv2.w;
                acc[i].x += xv.w * wv3.x; acc[i].y += xv.w * wv3.y;
                acc[i].z += xv.w * wv3.z; acc[i].w += xv.w * wv3.w;
            }
        }
    }

    float4 ka = *(const float4*)(kA + c4);
    float4 kb = *(const float4*)(kB + c4);
#pragma unroll
    for (int i = 0; i < 4; ++i) {
        int node = base + ng * 4 + i;
        if (node >= n) continue;
        float4 a = acc[i];
        float4 v;
        v.x = fmaxf(a.x * ka.x + kb.x, 0.f);
        v.y = fmaxf(a.y * ka.y + kb.y, 0.f);
        v.z = fmaxf(a.z * ka.z + kb.z, 0.f);
        v.w = fmaxf(a.w * ka.w + kb.w, 0.f);
        size_t slot = (size_t)(c4 >> 4) * ((size_t)n * 16) + (size_t)node * 16 + (c4 & 15);
        if (RES) {
            float4 rv = *(const float4*)(res + slot);
            v.x += rv.x; v.y += rv.y; v.z += rv.z; v.w += rv.w;
        }
        *(float4*)(outs + slot) = v;
    }
}

// ---------------------------------------------------------------------------
// Per-graph mean-pool + final linear. batch is SORTED: graph g owns a
// contiguous node range found by binary search. No atomics anywhere.
// 128 threads/block; thread c owns channel c (sliced-16 input layout).
__global__ __launch_bounds__(128) void k_poolfinal(
    const float* __restrict__ Hs, const int* __restrict__ batch,
    const float* __restrict__ Wf, const float* __restrict__ bf,
    float* __restrict__ out, int n) {
    int g = blockIdx.x;
    int t = threadIdx.x;
    // lower_bound(g) and lower_bound(g+1)
    int lo = 0, hi = n;
    while (lo < hi) { int m = (lo + hi) >> 1; if (batch[m] < g) lo = m + 1; else hi = m; }
    int start = lo;
    lo = 0; hi = n;
    while (lo < hi) { int m = (lo + hi) >> 1; if (batch[m] < g + 1) lo = m + 1; else hi = m; }
    int end = lo;

    const float* base = Hs + (size_t)(t >> 4) * ((size_t)n * 16) + (t & 15);
    float acc = 0.f;
    for (int i = start; i < end; ++i) acc += base[(size_t)i * 16];
    float v = acc * Wf[t];

    __shared__ float red[128];
    red[t] = v;
    __syncthreads();
    for (int s = 64; s > 0; s >>= 1) {
        if (t < s) red[t] += red[t + s];
        __syncthreads();
    }
    if (t == 0) out[g] = red[0] / fmaxf((float)(end - start), 1.f) + bf[0];
}

// ---------------------------------------------------------------------------
extern "C" void kernel_launch(void* const* d_in, const int* in_sizes, int n_in,
                              void* d_out, int out_size, void* d_ws, size_t ws_size,
                              hipStream_t stream) {
    const float* x     = (const float*)d_in[0];
    const int*   ei    = (const int*)d_in[1];
    const int*   src   = ei;
    const int*   dst   = ei + N_EDGES;
    const float* w     = (const float*)d_in[2];
    const int*   batch = (const int*)d_in[3];
    const float* W1 = (const float*)d_in[4];
    const float* b1 = (const float*)d_in[5];
    const float* W2 = (const float*)d_in[6];
    const float* b2 = (const float*)d_in[7];
    const float* W3 = (const float*)d_in[8];
    const float* b3 = (const float*)d_in[9];
    const float* Wf = (const float*)d_in[10];
    const float* bf = (const float*)d_in[11];
    const float* g1 = (const float*)d_in[12];
    const float* be1 = (const float*)d_in[13];
    const float* m1 = (const float*)d_in[14];
    const float* v1 = (const float*)d_in[15];
    const float* g2 = (const float*)d_in[16];
    const float* be2 = (const float*)d_in[17];
    const float* m2 = (const float*)d_in[18];
    const float* v2 = (const float*)d_in[19];
    const float* g3 = (const float*)d_in[20];
    const float* be3 = (const float*)d_in[21];
    const float* m3 = (const float*)d_in[22];
    const float* v3 = (const float*)d_in[23];

    float* out = (float*)d_out;

    // Workspace layout (all sections 16B-aligned)
    float* ws    = (float*)d_ws;
    float* out2s = ws;                                    // N*128 sliced-16 (L2 out / res / L3 out in-place)
    float* buf2  = out2s + (size_t)N_NODES * 128;         // N*128: agg2 (N*64) then agg3s
    float* agg2  = buf2;                                  // plain [node][64]
    int2*  csr   = (int2*)(buf2 + (size_t)N_NODES * 128); // E
    float* wdeg  = (float*)(csr + N_EDGES);               // N (becomes dinv)
    int*   cnt_i = (int*)(wdeg + N_NODES);                // N
    int*   cursor = cnt_i + N_NODES;                      // N (reused as aggx)
    float* aggx  = (float*)cursor;
    float* kA1   = (float*)(cursor + N_NODES);            // 64
    float* kB1   = kA1 + 64;                              // 64
    float* kA2   = kB1 + 64;                              // 128
    float* kB2   = kA2 + 128;                             // 128
    float* kA3   = kB2 + 128;                             // 128
    float* kB3   = kA3 + 128;                             // 128
    int*   offs  = (int*)(kB3 + 128);                     // N+1
    int*   bsum  = offs + N_NODES + 1;                    // SCAN_NB
    int*   bpre  = bsum + SCAN_NB;                        // SCAN_NB

    const int BS = 256;
    auto nb = [](long n) { return (int)((n + 255) / 256); };

    hipMemsetAsync(wdeg, 0, N_NODES * sizeof(float), stream);
    hipMemsetAsync(cnt_i, 0, N_NODES * sizeof(int), stream);

    // --- CSR build + degree norm ---
    k_degcnt<<<nb(N_EDGES), BS, 0, stream>>>(dst, w, wdeg, cnt_i, N_EDGES);
    k_scan1<<<SCAN_NB, 256, 0, stream>>>(cnt_i, bsum, N_NODES);
    k_scan2<<<1, 256, 0, stream>>>(bsum, bpre, SCAN_NB);
    k_scan3<<<SCAN_NB, 256, 0, stream>>>(cnt_i, bpre, offs, cursor, N_NODES);
    k_dinv<<<nb(N_NODES), BS, 0, stream>>>(wdeg, N_NODES);
    float* dinv = wdeg;
    k_fill<<<nb(N_EDGES), BS, 0, stream>>>(src, dst, w, dinv, cursor, csr, N_EDGES);
    k_bnprep_all<<<1, 320, 0, stream>>>(W1, b1, g1, be1, m1, v1, b2, g2, be2, m2, v2,
                                        b3, g3, be3, m3, v3, kA1, kB1, kA2, kB2, kA3, kB3);

    // --- Layer 1 aggregate (scalar) ---
    k_aggx<<<nb(N_NODES), BS, 0, stream>>>(offs, csr, x, dinv, aggx, N_NODES);

    // --- Layer 2: fused L1-matmul + aggregate, then 64->128 matmul ---
    k_gather2F<<<nb((long)N_NODES * 16), BS, 0, stream>>>(
        offs, csr, aggx, dinv, kA1, kB1, agg2, N_NODES);
    k_mmT<64, 1, false><<<(N_NODES + 31) / 32, BS, 0, stream>>>(
        agg2, W2, kA2, kB2, nullptr, out2s, N_NODES);

    // --- Layer 3: sliced aggregate, matmul + affine + relu + residual (in-place) ---
    k_gatherS16<<<8 * ((N_NODES + 63) / 64), BS, 0, stream>>>(
        offs, csr, out2s, dinv, buf2, N_NODES);
    k_mmT<128, 8, true><<<(N_NODES + 31) / 32, BS, 0, stream>>>(
        buf2, W3, kA3, kB3, out2s, out2s, N_NODES);

    // --- per-graph mean pool + final linear (batch sorted, no atomics) ---
    k_poolfinal<<<N_GRAPHS, 128, 0, stream>>>(out2s, batch, Wf, bf, out, N_NODES);
}